// Round 6
// baseline (234.953 us; speedup 1.0000x reference)
//
#include <hip/hip_runtime.h>
#include <hip/hip_bf16.h>
#include <stdint.h>

#define NTOK 8192
#define DIN  256
#define DOUT 256
#define NEXP 16
#define HID  512
#define NKA  (NTOK*2)    // total assignments
#define NBLK (NTOK/256)  // fill2 blocks
#define NRBLK (NTOK/8)   // routing hist blocks (8 tokens each)
#define MAXTILE 272      // sum ceil(Te/64) <= 16384/64 + 16
#define GK 768           // gate split-GEMM K: [x_hi | x_lo | x_hi]

typedef __bf16 bf16x8 __attribute__((ext_vector_type(8)));
typedef __bf16 bf16x4 __attribute__((ext_vector_type(4)));
typedef float  f32x4  __attribute__((ext_vector_type(4)));

// async 16B global -> LDS (DMA; wave-uniform LDS base + lane*16)
__device__ __forceinline__ void async_cp16(const __bf16* g, __bf16* l) {
  __builtin_amdgcn_global_load_lds(
      (const __attribute__((address_space(1))) unsigned int*)g,
      (__attribute__((address_space(3))) unsigned int*)l, 16, 0, 0);
}

// ---------------- fused prep: cvt_x + gate_w_split + 3x transpose_cvt + zero(out) -----
__device__ __forceinline__ void transpose_cvt_body(const float* __restrict__ src,
                                                   __bf16* __restrict__ dst,
                                                   int K, int N, int bx, int by, int bz,
                                                   int tx, int ty, float (*t)[33]) {
  int e = bz, k0 = bx * 32, n0 = by * 32;
  #pragma unroll
  for (int j = 0; j < 4; j++) {
    int kl = ty + j * 8;
    t[kl][tx] = src[(size_t)(k0 + kl) * (NEXP * N) + (size_t)e * N + n0 + tx];
  }
  __syncthreads();
  #pragma unroll
  for (int j = 0; j < 4; j++) {
    int nl = ty + j * 8;
    dst[(size_t)e * N * K + (size_t)(n0 + nl) * K + k0 + tx] = (__bf16)t[tx][nl];
  }
}

__global__ __launch_bounds__(256) void prep_kernel(
    const float* __restrict__ x, __bf16* __restrict__ xb, __bf16* __restrict__ xs,
    const float* __restrict__ gw, __bf16* __restrict__ gwt,
    const float* __restrict__ w1, __bf16* __restrict__ w1t,
    const float* __restrict__ w2, __bf16* __restrict__ w2t,
    const float* __restrict__ w3, __bf16* __restrict__ w3t,
    int* __restrict__ gtile_e, int* __restrict__ gtile_mt,
    int* __restrict__ gntiles, int* __restrict__ gseg,
    float* __restrict__ outz) {
  __shared__ float t[32][33];
  int idx = blockIdx.x;
  int tid = threadIdx.x;
  int tx = tid & 31, ty = tid >> 5;
  if (idx < 2048) {
    // cvt_x: fp32 -> bf16 hi (xb) + bf16x2 split (xs)
    int i = idx * 256 + tid;
    float4 v = ((const float4*)x)[i];
    int base = i * 4;
    int tk = base >> 8, c = base & 255;
    bf16x4 hi = { (__bf16)v.x, (__bf16)v.y, (__bf16)v.z, (__bf16)v.w };
    bf16x4 lo = { (__bf16)(v.x - (float)hi[0]), (__bf16)(v.y - (float)hi[1]),
                  (__bf16)(v.z - (float)hi[2]), (__bf16)(v.w - (float)hi[3]) };
    *(bf16x4*)(xb + (size_t)tk * DIN + c) = hi;
    __bf16* row = xs + (size_t)tk * GK + c;
    *(bf16x4*)(row)       = hi;
    *(bf16x4*)(row + 256) = lo;
    *(bf16x4*)(row + 512) = hi;
  } else if (idx < 2176) {
    // gate weight: transpose + bf16x2 split into B^T layout [n][GK]
    int g = idx - 2048;
    int k0 = (g & 7) * 32, n0 = (g >> 3) * 32;
    #pragma unroll
    for (int j = 0; j < 4; j++) {
      int kl = ty + j * 8;
      t[kl][tx] = gw[(size_t)(k0 + kl) * HID + n0 + tx];
    }
    __syncthreads();
    #pragma unroll
    for (int j = 0; j < 4; j++) {
      int nl = ty + j * 8;
      float v = t[tx][nl];
      __bf16 hi = (__bf16)v;
      __bf16 lo = (__bf16)(v - (float)hi);
      __bf16* drow = gwt + (size_t)(n0 + nl) * GK + k0 + tx;
      drow[0]   = hi;
      drow[256] = hi;
      drow[512] = lo;
    }
    if (g == 0) {
      if (tid < 128) { gtile_e[tid] = 0; gtile_mt[tid] = tid; }
      else if (tid == 128) { *gntiles = 128; }
      else if (tid == 129) { gseg[0] = 0; gseg[1] = NTOK; }
    }
  } else if (idx < 4224) {
    int g = idx - 2176;  // w1: K=256 (8), N=512 (16), E=16
    transpose_cvt_body(w1, w1t, DIN, HID, g & 7, (g >> 3) & 15, g >> 7, tx, ty, t);
  } else if (idx < 8320) {
    int g = idx - 4224;  // w2: K=512 (16), N=512 (16), E=16
    transpose_cvt_body(w2, w2t, HID, HID, g & 15, (g >> 4) & 15, g >> 8, tx, ty, t);
  } else if (idx < 10368) {
    int g = idx - 8320;  // w3: K=512 (16), N=256 (8), E=16
    transpose_cvt_body(w3, w3t, HID, DOUT, g & 15, (g >> 4) & 7, g >> 7, tx, ty, t);
  } else {
    // zero the final output (GEMM-3 combines via atomicAdd)
    int i = (idx - 10368) * 256 + tid;
    ((float4*)outz)[i] = make_float4(0.f, 0.f, 0.f, 0.f);
  }
}

// ------- fused route: logits (from hg) + top-2 + softmax + 8-token hist/ranks -------
__global__ __launch_bounds__(128) void route_kernel(const float* __restrict__ hg,
                                                    const float* __restrict__ gw,
                                                    const float* __restrict__ gb,
                                                    int2* __restrict__ e01,
                                                    float2* __restrict__ g01,
                                                    int* __restrict__ lrank,
                                                    int* __restrict__ blockhist) {
  __shared__ float hl[8][HID + 8];   // +8 pad: kills 4-way bank conflict on dot loop
  __shared__ float wl[HID][16];
  __shared__ float ls[8][16];
  __shared__ int bhist[NEXP];
  int t0 = blockIdx.x * 8;
  int tid = threadIdx.x;
  if (tid < NEXP) bhist[tid] = 0;
  for (int c = tid; c < 8 * (HID / 4); c += 128) {
    int row = c >> 7, col = (c & 127) * 4;
    *(float4*)&hl[row][col] = *(const float4*)&hg[(size_t)(t0 + row) * HID + col];
  }
  for (int c = tid; c < HID * 4; c += 128) {
    int k = c >> 2, e4 = (c & 3) * 4;
    *(float4*)&wl[k][e4] = *(const float4*)&gw[(size_t)k * 16 + e4];
  }
  __syncthreads();
  int tok = tid >> 4, e = tid & 15;
  float s = gb[e];
  #pragma unroll 8
  for (int k = 0; k < HID; k++) s = fmaf(hl[tok][k], wl[k][e], s);
  ls[tok][e] = s;
  __syncthreads();
  if (tid < 8) {
    int t = t0 + tid;
    float v0 = -3.402823466e38f, v1 = -3.402823466e38f;
    int i0 = 0, i1 = 0;
    #pragma unroll
    for (int ee = 0; ee < 16; ee++) {
      float v = ls[tid][ee];
      if (v > v0) { v1 = v0; i1 = i0; v0 = v; i0 = ee; }
      else if (v > v1) { v1 = v; i1 = ee; }
    }
    float ew = expf(v1 - v0);
    float inv = 1.f / (1.f + ew);
    e01[t] = make_int2(i0, i1);
    g01[t] = make_float2(inv, ew * inv);
    int r0 = atomicAdd(&bhist[i0], 1);
    int r1 = atomicAdd(&bhist[i1], 1);
    lrank[2 * t]     = r0;
    lrank[2 * t + 1] = r1;
  }
  __syncthreads();
  if (tid < NEXP) blockhist[blockIdx.x * NEXP + tid] = bhist[tid];
}

// ------- scan: expert offsets, per-(rblock,expert) base, flat TILE LIST (parallel) -----
__global__ __launch_bounds__(256) void scan2_kernel(const int* __restrict__ blockhist,
                                                    int* __restrict__ offsets,
                                                    int* __restrict__ base,
                                                    int* __restrict__ tile_e,
                                                    int* __restrict__ tile_mt,
                                                    int* __restrict__ ntiles) {
  __shared__ int part[NEXP][16];    // [e][chunk] sums, chunks of 64 rblocks
  __shared__ int cbase[NEXP][16];   // exclusive prefix over chunks
  __shared__ int tot[NEXP];
  __shared__ int soff[NEXP + 1];
  __shared__ int tbase[NEXP];
  int tid = threadIdx.x;
  int e = tid & 15, c = tid >> 4;   // 16 experts x 16 chunks
  int s = 0;
  for (int i = 0; i < 64; i++) s += blockhist[(size_t)(c * 64 + i) * NEXP + e];
  part[e][c] = s;
  __syncthreads();
  if (tid < NEXP) {
    int t = 0;
    for (int c2 = 0; c2 < 16; c2++) { cbase[tid][c2] = t; t += part[tid][c2]; }
    tot[tid] = t;
  }
  __syncthreads();
  if (tid == 0) {
    int acc = 0, tb = 0;
    for (int i = 0; i < NEXP; i++) {
      soff[i] = acc; acc += tot[i];
      tbase[i] = tb; tb += (tot[i] + 63) >> 6;
    }
    soff[NEXP] = acc;
    *ntiles = tb;
  }
  __syncthreads();
  if (tid < NEXP + 1) offsets[tid] = soff[tid];
  {
    int run = soff[e] + cbase[e][c];
    for (int i = 0; i < 64; i++) {
      int b = c * 64 + i;
      base[(size_t)b * NEXP + e] = run;
      run += blockhist[(size_t)b * NEXP + e];
    }
  }
  if (tid < NEXP) {
    int nt = (tot[tid] + 63) >> 6, tb = tbase[tid];
    for (int m = 0; m < nt; m++) { tile_e[tb + m] = tid; tile_mt[tb + m] = m; }
  }
}

// -------- fill: atomic-free scatter using (base, lrank); also emits gate weight -------
__global__ __launch_bounds__(256) void fill2_kernel(const int2* __restrict__ e01,
                                                    const int* __restrict__ lrank,
                                                    const int* __restrict__ base,
                                                    const float2* __restrict__ g01,
                                                    int* __restrict__ tok_sorted,
                                                    int* __restrict__ route_pos,
                                                    float* __restrict__ gw_sorted) {
  int t = blockIdx.x * 256 + threadIdx.x;
  int2 e = e01[t];
  float2 g = g01[t];
  int b = t >> 3;
  int p0 = base[(size_t)b * NEXP + e.x] + lrank[2 * t];
  int p1 = base[(size_t)b * NEXP + e.y] + lrank[2 * t + 1];
  tok_sorted[p0] = t; route_pos[2 * t]     = p0; gw_sorted[p0] = g.x;
  tok_sorted[p1] = t; route_pos[2 * t + 1] = p1; gw_sorted[p1] = g.y;
}

// ------- grouped expert GEMM: TM=64, TN=128, BK=32, dbuf async LDS, tile-list grid ----
// MODE: 0 = bf16 store, 1 = f32 store, 2 = fused gate-combine (atomicAdd into out)
template<int MODE, bool RELU>
__global__ __launch_bounds__(256) void moe_gemm_kernel(const __bf16* __restrict__ A,
                                                       const __bf16* __restrict__ Bt,
                                                       const float* __restrict__ bias,
                                                       void* __restrict__ out,
                                                       const int* __restrict__ seg_off,
                                                       const int* __restrict__ gather,
                                                       const int* __restrict__ tile_e,
                                                       const int* __restrict__ tile_mt,
                                                       const int* __restrict__ ntiles,
                                                       const int* __restrict__ tok_s,
                                                       const float* __restrict__ gws,
                                                       int K, int N) {
  int bx = blockIdx.x;
  if (bx >= *ntiles) return;
  int e  = tile_e[bx];
  int mt = tile_mt[bx];
  int off = seg_off[e];
  int Te  = seg_off[e + 1] - off;
  int nt = blockIdx.y;

  __shared__ __bf16 Al[2][64][32];
  __shared__ __bf16 Bl[2][128][32];

  int tid = threadIdx.x;
  int lane = tid & 63, w = tid >> 6;
  int l16 = lane & 15, quad = lane >> 4;

  int r0 = tid >> 2;
  int q8 = ((tid & 3) ^ ((r0 >> 1) & 3)) * 8;  // slot swizzle (both sides)
  int rowA = mt * 64 + r0;
  int rA = rowA < Te ? rowA : Te - 1;
  size_t ga = gather ? (size_t)gather[off + rA] : (size_t)(off + rA);
  const __bf16* apg  = A + ga * K + q8;
  const __bf16* Bte  = Bt + (size_t)e * N * K;
  const __bf16* bpg0 = Bte + (size_t)(nt * 128 + r0) * K + q8;
  const __bf16* bpg1 = bpg0 + (size_t)64 * K;

  __bf16* al0 = &Al[0][0][0];
  __bf16* al1 = &Al[1][0][0];
  __bf16* bl0 = &Bl[0][0][0];
  __bf16* bl1 = &Bl[1][0][0];

  f32x4 acc[4][2];
  #pragma unroll
  for (int i = 0; i < 4; i++)
    #pragma unroll
    for (int j = 0; j < 2; j++) acc[i][j] = {0.f, 0.f, 0.f, 0.f};

  async_cp16(apg, al0 + tid * 8);
  async_cp16(bpg0, bl0 + tid * 8);
  async_cp16(bpg1, bl0 + (tid + 256) * 8);

  int qs = (quad ^ ((l16 >> 1) & 3)) * 8;

  int nIter = K >> 5;
  for (int it = 0; it < nIter; ++it) {
    int buf = it & 1;
    if (it + 1 < nIter) {
      int kb = (it + 1) << 5;
      __bf16* an = buf ? al0 : al1;
      __bf16* bn = buf ? bl0 : bl1;
      async_cp16(apg + kb, an + tid * 8);
      async_cp16(bpg0 + kb, bn + tid * 8);
      async_cp16(bpg1 + kb, bn + (tid + 256) * 8);
      asm volatile("s_waitcnt vmcnt(3)" ::: "memory");
    } else {
      asm volatile("s_waitcnt vmcnt(0)" ::: "memory");
    }
    __builtin_amdgcn_s_barrier();
    asm volatile("" ::: "memory");
    const __bf16* ab = buf ? al1 : al0;
    const __bf16* bb = buf ? bl1 : bl0;
    bf16x8 af[4], bfr[2];
    #pragma unroll
    for (int i = 0; i < 4; i++)
      af[i] = *(const bf16x8*)(ab + (size_t)(i * 16 + l16) * 32 + qs);
    #pragma unroll
    for (int i = 0; i < 2; i++)
      bfr[i] = *(const bf16x8*)(bb + (size_t)(w * 32 + i * 16 + l16) * 32 + qs);
    #pragma unroll
    for (int mi = 0; mi < 4; mi++)
      #pragma unroll
      for (int ni = 0; ni < 2; ni++)
        acc[mi][ni] = __builtin_amdgcn_mfma_f32_16x16x32_bf16(af[mi], bfr[ni], acc[mi][ni], 0, 0, 0);
    asm volatile("" ::: "memory");
    __builtin_amdgcn_s_barrier();
  }

  const float* be = bias + (size_t)e * N;
  if (MODE == 2) {
    float bv[2];
    #pragma unroll
    for (int ni = 0; ni < 2; ni++) bv[ni] = be[nt * 128 + w * 32 + ni * 16 + l16];
    #pragma unroll
    for (int mi = 0; mi < 4; mi++) {
      #pragma unroll
      for (int r = 0; r < 4; r++) {
        int row_in = mt * 64 + mi * 16 + quad * 4 + r;
        if (row_in < Te) {
          int p = off + row_in;
          int t = tok_s[p];
          float gv = gws[p];
          #pragma unroll
          for (int ni = 0; ni < 2; ni++) {
            int col = nt * 128 + w * 32 + ni * 16 + l16;
            atomicAdd((float*)out + (size_t)t * N + col, (acc[mi][ni][r] + bv[ni]) * gv);
          }
        }
      }
    }
  } else {
    #pragma unroll
    for (int ni = 0; ni < 2; ni++) {
      int col = nt * 128 + w * 32 + ni * 16 + l16;
      float bv = be[col];
      #pragma unroll
      for (int mi = 0; mi < 4; mi++) {
        #pragma unroll
        for (int r = 0; r < 4; r++) {
          int row_in = mt * 64 + mi * 16 + quad * 4 + r;
          if (row_in < Te) {
            float v = acc[mi][ni][r] + bv;
            if (RELU) v = fmaxf(v, 0.f);
            size_t orow = (size_t)(off + row_in);
            if (MODE == 1) ((float*)out)[orow * N + col] = v;
            else ((__bf16*)out)[orow * N + col] = (__bf16)v;
          }
        }
      }
    }
  }
}

// ---------------- launcher ----------------
extern "C" void kernel_launch(void* const* d_in, const int* in_sizes, int n_in,
                              void* d_out, int out_size, void* d_ws, size_t ws_size,
                              hipStream_t stream) {
  const float* x          = (const float*)d_in[0];
  const float* gate_w     = (const float*)d_in[1];
  const float* gate_b     = (const float*)d_in[2];
  const float* gate_out_w = (const float*)d_in[3];
  const float* gate_out_b = (const float*)d_in[4];
  const float* w1         = (const float*)d_in[5];
  const float* b1         = (const float*)d_in[6];
  const float* w2         = (const float*)d_in[7];
  const float* b2         = (const float*)d_in[8];
  const float* w3         = (const float*)d_in[9];
  const float* b3         = (const float*)d_in[10];
  float* out = (float*)d_out;

  char* ws = (char*)d_ws;
  size_t o = 0;
  auto alloc = [&](size_t bytes) -> void* {
    o = (o + 255) & ~(size_t)255;
    void* p = ws + o;
    o += bytes;
    return p;
  };

  __bf16* xb   = (__bf16*)alloc((size_t)NTOK * DIN * 2);
  __bf16* w1t  = (__bf16*)alloc((size_t)NEXP * HID * DIN * 2);
  __bf16* w2t  = (__bf16*)alloc((size_t)NEXP * HID * HID * 2);
  __bf16* w3t  = (__bf16*)alloc((size_t)NEXP * DOUT * HID * 2);
  __bf16* gwt  = (__bf16*)alloc((size_t)HID * GK * 2);
  size_t r1 = (size_t)NTOK * HID * 4;
  size_t r2 = (size_t)(NKA + 128) * HID * 2;
  void* region1 = alloc(r1 > r2 ? r1 : r2);   // hg (fp32) aliases H1 (bf16); hg dead first
  float*  hg = (float*)region1;
  __bf16* H1 = (__bf16*)region1;
  // xs (gate split input, dead after gate GEMM) aliases H2 (written much later)
  size_t r3 = (size_t)NTOK * GK * 2;
  size_t r4 = (size_t)(NKA + 128) * HID * 2;
  void* region2 = alloc(r3 > r4 ? r3 : r4);
  __bf16* xs = (__bf16*)region2;
  __bf16* H2 = (__bf16*)region2;
  int2*  e01       = (int2*)alloc((size_t)NTOK * 8);
  float2* g01      = (float2*)alloc((size_t)NTOK * 8);
  int*   offsets   = (int*)alloc((NEXP + 1) * 4);
  int*   blockhist = (int*)alloc((size_t)NRBLK * NEXP * 4);
  int*   base      = (int*)alloc((size_t)NRBLK * NEXP * 4);
  int*   lrank     = (int*)alloc((size_t)NTOK * 2 * 4);
  int*   tok_sorted= (int*)alloc((size_t)(NKA + 128) * 4);
  int*   route_pos = (int*)alloc((size_t)NTOK * 2 * 4);
  float* gw_sorted = (float*)alloc((size_t)(NKA + 128) * 4);
  int*   tile_e    = (int*)alloc(MAXTILE * 4);
  int*   tile_mt   = (int*)alloc(MAXTILE * 4);
  int*   ntiles    = (int*)alloc(4);
  int*   gtile_e   = (int*)alloc(128 * 4);
  int*   gtile_mt  = (int*)alloc(128 * 4);
  int*   gntiles   = (int*)alloc(4);
  int*   gseg      = (int*)alloc(2 * 4);
  (void)ws_size; (void)n_in; (void)in_sizes; (void)out_size;

  // 1. fused prep (cvt_x + gate weight split + 3 weight transposes + zero(out))
  prep_kernel<<<12416, 256, 0, stream>>>(x, xb, xs, gate_w, gwt,
                                         w1, w1t, w2, w2t, w3, w3t,
                                         gtile_e, gtile_mt, gntiles, gseg, out);

  // 2. gate GEMM via MFMA, bf16x2-split K=768
  moe_gemm_kernel<1, true><<<dim3(NTOK / 64, HID / 128), 256, 0, stream>>>(
      xs, gwt, gate_b, hg, gseg, nullptr, gtile_e, gtile_mt, gntiles,
      nullptr, nullptr, GK, HID);

  // 3. fused logits + top-2 routing
  route_kernel<<<NTOK / 8, 128, 0, stream>>>(hg, gate_out_w, gate_out_b,
                                             e01, g01, lrank, blockhist);
  // 4-5. scan + fill
  scan2_kernel<<<1, 256, 0, stream>>>(blockhist, offsets, base, tile_e, tile_mt, ntiles);
  fill2_kernel<<<NBLK, 256, 0, stream>>>(e01, lrank, base, g01,
                                         tok_sorted, route_pos, gw_sorted);

  // 6-8. expert GEMMs; GEMM-3 fuses the gate-weighted combine via atomicAdd
  moe_gemm_kernel<0, true><<<dim3(MAXTILE, HID / 128), 256, 0, stream>>>(
      xb, w1t, b1, H1, offsets, tok_sorted, tile_e, tile_mt, ntiles,
      nullptr, nullptr, DIN, HID);
  moe_gemm_kernel<0, true><<<dim3(MAXTILE, HID / 128), 256, 0, stream>>>(
      H1, w2t, b2, H2, offsets, nullptr, tile_e, tile_mt, ntiles,
      nullptr, nullptr, HID, HID);
  moe_gemm_kernel<2, false><<<dim3(MAXTILE, DOUT / 128), 256, 0, stream>>>(
      H2, w3t, b3, out, offsets, nullptr, tile_e, tile_mt, ntiles,
      tok_sorted, gw_sorted, HID, DOUT);
}

// Round 7
// 202.523 us; speedup vs baseline: 1.1601x; 1.1601x over previous
//
#include <hip/hip_runtime.h>
#include <hip/hip_bf16.h>
#include <stdint.h>

#define NTOK 8192
#define DIN  256
#define DOUT 256
#define NEXP 16
#define HID  512
#define NKA  (NTOK*2)    // total assignments
#define NBLK (NTOK/256)  // routing/fill blocks (256 tokens each)
#define MAXTILE 272      // sum ceil(Te/64) <= 16384/64 + 16
#define GK 768           // gate split-GEMM K: [x_hi | x_lo | x_hi]

typedef __bf16 bf16x8 __attribute__((ext_vector_type(8)));
typedef __bf16 bf16x4 __attribute__((ext_vector_type(4)));
typedef float  f32x4  __attribute__((ext_vector_type(4)));

// async 16B global -> LDS (DMA; wave-uniform LDS base + lane*16)
__device__ __forceinline__ void async_cp16(const __bf16* g, __bf16* l) {
  __builtin_amdgcn_global_load_lds(
      (const __attribute__((address_space(1))) unsigned int*)g,
      (__attribute__((address_space(3))) unsigned int*)l, 16, 0, 0);
}

// ------ fused prep: cvt_x + gate_w_split + 3x transpose_cvt + zero(logits) ------
__device__ __forceinline__ void transpose_cvt_body(const float* __restrict__ src,
                                                   __bf16* __restrict__ dst,
                                                   int K, int N, int bx, int by, int bz,
                                                   int tx, int ty, float (*t)[33]) {
  int e = bz, k0 = bx * 32, n0 = by * 32;
  #pragma unroll
  for (int j = 0; j < 4; j++) {
    int kl = ty + j * 8;
    t[kl][tx] = src[(size_t)(k0 + kl) * (NEXP * N) + (size_t)e * N + n0 + tx];
  }
  __syncthreads();
  #pragma unroll
  for (int j = 0; j < 4; j++) {
    int nl = ty + j * 8;
    dst[(size_t)e * N * K + (size_t)(n0 + nl) * K + k0 + tx] = (__bf16)t[tx][nl];
  }
}

__global__ __launch_bounds__(256) void prep_kernel(
    const float* __restrict__ x, __bf16* __restrict__ xb, __bf16* __restrict__ xs,
    const float* __restrict__ gw, __bf16* __restrict__ gwt,
    const float* __restrict__ w1, __bf16* __restrict__ w1t,
    const float* __restrict__ w2, __bf16* __restrict__ w2t,
    const float* __restrict__ w3, __bf16* __restrict__ w3t,
    int* __restrict__ gtile_e, int* __restrict__ gtile_mt,
    int* __restrict__ gntiles, int* __restrict__ gseg,
    float* __restrict__ logitz) {
  __shared__ float t[32][33];
  int idx = blockIdx.x;
  int tid = threadIdx.x;
  int tx = tid & 31, ty = tid >> 5;
  if (idx < 2048) {
    // cvt_x: fp32 -> bf16 hi (xb) + bf16x2 split (xs)
    int i = idx * 256 + tid;
    float4 v = ((const float4*)x)[i];
    int base = i * 4;
    int tk = base >> 8, c = base & 255;
    bf16x4 hi = { (__bf16)v.x, (__bf16)v.y, (__bf16)v.z, (__bf16)v.w };
    bf16x4 lo = { (__bf16)(v.x - (float)hi[0]), (__bf16)(v.y - (float)hi[1]),
                  (__bf16)(v.z - (float)hi[2]), (__bf16)(v.w - (float)hi[3]) };
    *(bf16x4*)(xb + (size_t)tk * DIN + c) = hi;
    __bf16* row = xs + (size_t)tk * GK + c;
    *(bf16x4*)(row)       = hi;
    *(bf16x4*)(row + 256) = lo;
    *(bf16x4*)(row + 512) = hi;
  } else if (idx < 2176) {
    // gate weight: transpose + bf16x2 split into B^T layout [n][GK]
    int g = idx - 2048;
    int k0 = (g & 7) * 32, n0 = (g >> 3) * 32;
    #pragma unroll
    for (int j = 0; j < 4; j++) {
      int kl = ty + j * 8;
      t[kl][tx] = gw[(size_t)(k0 + kl) * HID + n0 + tx];
    }
    __syncthreads();
    #pragma unroll
    for (int j = 0; j < 4; j++) {
      int nl = ty + j * 8;
      float v = t[tx][nl];
      __bf16 hi = (__bf16)v;
      __bf16 lo = (__bf16)(v - (float)hi);
      __bf16* drow = gwt + (size_t)(n0 + nl) * GK + k0 + tx;
      drow[0]   = hi;
      drow[256] = hi;
      drow[512] = lo;
    }
    if (g == 0) {
      if (tid < 128) { gtile_e[tid] = 0; gtile_mt[tid] = tid; }
      else if (tid == 128) { *gntiles = 128; }
      else if (tid == 129) { gseg[0] = 0; gseg[1] = NTOK; }
    }
  } else if (idx < 4224) {
    int g = idx - 2176;  // w1: K=256 (8), N=512 (16), E=16
    transpose_cvt_body(w1, w1t, DIN, HID, g & 7, (g >> 3) & 15, g >> 7, tx, ty, t);
  } else if (idx < 8320) {
    int g = idx - 4224;  // w2: K=512 (16), N=512 (16), E=16
    transpose_cvt_body(w2, w2t, HID, HID, g & 15, (g >> 4) & 15, g >> 8, tx, ty, t);
  } else if (idx < 10368) {
    int g = idx - 8320;  // w3: K=512 (16), N=256 (8), E=16
    transpose_cvt_body(w3, w3t, HID, DOUT, g & 15, (g >> 4) & 7, g >> 7, tx, ty, t);
  } else {
    // zero the logits accumulator (gate GEMM combines partials via atomicAdd)
    int i = (idx - 10368) * 256 + tid;
    ((float4*)logitz)[i] = make_float4(0.f, 0.f, 0.f, 0.f);
  }
}

// ---------------- top-2 + softmax + block-local histogram/ranks ----------------
__global__ __launch_bounds__(256) void top2_kernel(const float* __restrict__ logits,
                                                   const float* __restrict__ gb,
                                                   int2* __restrict__ e01,
                                                   float2* __restrict__ g01,
                                                   int* __restrict__ lrank,
                                                   int* __restrict__ blockhist) {
  __shared__ int hist[NEXP];
  __shared__ float gbl[NEXP];
  int tid = threadIdx.x;
  if (tid < NEXP) { hist[tid] = 0; gbl[tid] = gb[tid]; }
  __syncthreads();
  int t = blockIdx.x * 256 + tid;
  float lv[16];
  const float4* lp = (const float4*)(logits + (size_t)t * 16);
  #pragma unroll
  for (int j = 0; j < 4; j++) {
    float4 v = lp[j];
    lv[4*j]   = v.x + gbl[4*j];
    lv[4*j+1] = v.y + gbl[4*j+1];
    lv[4*j+2] = v.z + gbl[4*j+2];
    lv[4*j+3] = v.w + gbl[4*j+3];
  }
  float v0 = -3.402823466e38f, v1 = -3.402823466e38f;
  int i0 = 0, i1 = 0;
  #pragma unroll
  for (int e = 0; e < 16; e++) {
    float v = lv[e];
    if (v > v0) { v1 = v0; i1 = i0; v0 = v; i0 = e; }
    else if (v > v1) { v1 = v; i1 = e; }
  }
  float ew = expf(v1 - v0);
  float inv = 1.f / (1.f + ew);
  e01[t] = make_int2(i0, i1);
  g01[t] = make_float2(inv, ew * inv);
  int r0 = atomicAdd(&hist[i0], 1);
  int r1 = atomicAdd(&hist[i1], 1);
  lrank[2 * t]     = r0;
  lrank[2 * t + 1] = r1;
  __syncthreads();
  if (tid < NEXP) blockhist[blockIdx.x * NEXP + tid] = hist[tid];
}

// ------- scan: expert offsets, per-(block,expert) base, and the flat TILE LIST -------
__global__ void scan2_kernel(const int* __restrict__ blockhist, int* __restrict__ offsets,
                             int* __restrict__ base, int* __restrict__ tile_e,
                             int* __restrict__ tile_mt, int* __restrict__ ntiles) {
  __shared__ int tot[NEXP];
  __shared__ int soff[NEXP + 1];
  __shared__ int tbase[NEXP];
  int e = threadIdx.x;
  if (e < NEXP) {
    int s = 0;
    for (int b = 0; b < NBLK; b++) s += blockhist[b * NEXP + e];
    tot[e] = s;
  }
  __syncthreads();
  if (e == 0) {
    int s = 0, tb = 0;
    for (int i = 0; i < NEXP; i++) {
      soff[i] = s; s += tot[i];
      tbase[i] = tb; tb += (tot[i] + 63) >> 6;
    }
    soff[NEXP] = s;
    *ntiles = tb;
  }
  __syncthreads();
  if (e < NEXP + 1) offsets[e] = soff[e];
  if (e < NEXP) {
    int s = soff[e];
    for (int b = 0; b < NBLK; b++) { base[b * NEXP + e] = s; s += blockhist[b * NEXP + e]; }
    int nt = (tot[e] + 63) >> 6, tb = tbase[e];
    for (int m = 0; m < nt; m++) { tile_e[tb + m] = e; tile_mt[tb + m] = m; }
  }
}

// ---------------- fill: atomic-free scatter using (base, lrank) ----------------
__global__ __launch_bounds__(256) void fill2_kernel(const int2* __restrict__ e01,
                                                    const int* __restrict__ lrank,
                                                    const int* __restrict__ base,
                                                    int* __restrict__ tok_sorted,
                                                    int* __restrict__ route_pos) {
  int b = blockIdx.x;
  int t = b * 256 + threadIdx.x;
  int2 e = e01[t];
  int p0 = base[b * NEXP + e.x] + lrank[2 * t];
  int p1 = base[b * NEXP + e.y] + lrank[2 * t + 1];
  tok_sorted[p0] = t; route_pos[2 * t]     = p0;
  tok_sorted[p1] = t; route_pos[2 * t + 1] = p1;
}

// ------- grouped expert GEMM: TM=64, TN=128, BK=32, dbuf async LDS, tile-list grid ----
// MODE: 0 = bf16 store, 1 = f32 store, 3 = gate logits epilogue (no hidden store:
//   relu'd 64x128 tile -> LDS fp32, partial dot vs gate_out_w slice, atomicAdd into
//   logits[t][e]; 512KB L2-resident target, 4 contributors per address).
template<int MODE, bool RELU>
__global__ __launch_bounds__(256) void moe_gemm_kernel(const __bf16* __restrict__ A,
                                                       const __bf16* __restrict__ Bt,
                                                       const float* __restrict__ bias,
                                                       void* __restrict__ out,
                                                       const int* __restrict__ seg_off,
                                                       const int* __restrict__ gather,
                                                       const int* __restrict__ tile_e,
                                                       const int* __restrict__ tile_mt,
                                                       const int* __restrict__ ntiles,
                                                       const float* __restrict__ gow,
                                                       int K, int N) {
  int bx = blockIdx.x;
  if (bx >= *ntiles) return;
  int e  = tile_e[bx];
  int mt = tile_mt[bx];
  int off = seg_off[e];
  int Te  = seg_off[e + 1] - off;
  int nt = blockIdx.y;

  // main staging needs 24576 B; MODE=3 epilogue overlay needs 8192 (wl) + 33792 (ht)
  constexpr int SMEM = (MODE == 3) ? (8192 + 64 * 132 * 4) : 24576;
  __shared__ __align__(16) char smem[SMEM];
  __bf16* AlB = (__bf16*)smem;           // [2][64][32]
  __bf16* BlB = (__bf16*)(smem + 8192);  // [2][128][32]

  int tid = threadIdx.x;
  int lane = tid & 63, w = tid >> 6;
  int l16 = lane & 15, quad = lane >> 4;

  int r0 = tid >> 2;
  int q8 = ((tid & 3) ^ ((r0 >> 1) & 3)) * 8;  // slot swizzle (both sides)
  int rowA = mt * 64 + r0;
  int rA = rowA < Te ? rowA : Te - 1;
  size_t ga = gather ? (size_t)gather[off + rA] : (size_t)(off + rA);
  const __bf16* apg  = A + ga * K + q8;
  const __bf16* Bte  = Bt + (size_t)e * N * K;
  const __bf16* bpg0 = Bte + (size_t)(nt * 128 + r0) * K + q8;
  const __bf16* bpg1 = bpg0 + (size_t)64 * K;

  __bf16* al0 = AlB;
  __bf16* al1 = AlB + 2048;
  __bf16* bl0 = BlB;
  __bf16* bl1 = BlB + 4096;

  f32x4 acc[4][2];
  #pragma unroll
  for (int i = 0; i < 4; i++)
    #pragma unroll
    for (int j = 0; j < 2; j++) acc[i][j] = {0.f, 0.f, 0.f, 0.f};

  async_cp16(apg, al0 + tid * 8);
  async_cp16(bpg0, bl0 + tid * 8);
  async_cp16(bpg1, bl0 + (tid + 256) * 8);

  int qs = (quad ^ ((l16 >> 1) & 3)) * 8;

  int nIter = K >> 5;
  for (int it = 0; it < nIter; ++it) {
    int buf = it & 1;
    if (it + 1 < nIter) {
      int kb = (it + 1) << 5;
      __bf16* an = buf ? al0 : al1;
      __bf16* bn = buf ? bl0 : bl1;
      async_cp16(apg + kb, an + tid * 8);
      async_cp16(bpg0 + kb, bn + tid * 8);
      async_cp16(bpg1 + kb, bn + (tid + 256) * 8);
      asm volatile("s_waitcnt vmcnt(3)" ::: "memory");
    } else {
      asm volatile("s_waitcnt vmcnt(0)" ::: "memory");
    }
    __builtin_amdgcn_s_barrier();
    asm volatile("" ::: "memory");
    const __bf16* ab = buf ? al1 : al0;
    const __bf16* bb = buf ? bl1 : bl0;
    bf16x8 af[4], bfr[2];
    #pragma unroll
    for (int i = 0; i < 4; i++)
      af[i] = *(const bf16x8*)(ab + (size_t)(i * 16 + l16) * 32 + qs);
    #pragma unroll
    for (int i = 0; i < 2; i++)
      bfr[i] = *(const bf16x8*)(bb + (size_t)(w * 32 + i * 16 + l16) * 32 + qs);
    #pragma unroll
    for (int mi = 0; mi < 4; mi++)
      #pragma unroll
      for (int ni = 0; ni < 2; ni++)
        acc[mi][ni] = __builtin_amdgcn_mfma_f32_16x16x32_bf16(af[mi], bfr[ni], acc[mi][ni], 0, 0, 0);
    asm volatile("" ::: "memory");
    __builtin_amdgcn_s_barrier();
  }

  const float* be = bias + (size_t)e * N;
  if (MODE == 3) {
    // ---- fused logits epilogue ----
    __syncthreads();
    float* wl = (float*)smem;              // [128][16]  gate_out_w slice
    float* ht = (float*)(smem + 8192);     // [64][132]  relu'd hidden tile (fp32)
    if (tid < 128) {
      const float* gr = gow + (size_t)(nt * 128 + tid) * 16;
      #pragma unroll
      for (int j = 0; j < 4; j++)
        *(float4*)&wl[tid * 16 + j * 4] = *(const float4*)&gr[j * 4];
    }
    float bv[2];
    #pragma unroll
    for (int ni = 0; ni < 2; ni++) bv[ni] = be[nt * 128 + w * 32 + ni * 16 + l16];
    #pragma unroll
    for (int mi = 0; mi < 4; mi++)
      #pragma unroll
      for (int ni = 0; ni < 2; ni++)
        #pragma unroll
        for (int r = 0; r < 4; r++) {
          int row = mi * 16 + quad * 4 + r;
          int col = w * 32 + ni * 16 + l16;
          ht[row * 132 + col] = fmaxf(acc[mi][ni][r] + bv[ni], 0.f);
        }
    __syncthreads();
    int t = tid >> 2, e4 = (tid & 3) * 4;
    float s0 = 0.f, s1 = 0.f, s2 = 0.f, s3 = 0.f;
    #pragma unroll 4
    for (int h = 0; h < 128; h++) {
      float hv = ht[t * 132 + h];
      const float* wr = &wl[h * 16 + e4];
      s0 = fmaf(hv, wr[0], s0);
      s1 = fmaf(hv, wr[1], s1);
      s2 = fmaf(hv, wr[2], s2);
      s3 = fmaf(hv, wr[3], s3);
    }
    float* lp = (float*)out + (size_t)(mt * 64 + t) * 16 + e4;
    atomicAdd(lp + 0, s0);
    atomicAdd(lp + 1, s1);
    atomicAdd(lp + 2, s2);
    atomicAdd(lp + 3, s3);
    return;
  }

  #pragma unroll
  for (int ni = 0; ni < 2; ni++) {
    int col = nt * 128 + w * 32 + ni * 16 + l16;
    float bv = be[col];
    #pragma unroll
    for (int mi = 0; mi < 4; mi++) {
      #pragma unroll
      for (int r = 0; r < 4; r++) {
        int row_in = mt * 64 + mi * 16 + quad * 4 + r;
        if (row_in < Te) {
          float v = acc[mi][ni][r] + bv;
          if (RELU) v = fmaxf(v, 0.f);
          size_t orow = (size_t)(off + row_in);
          if (MODE == 1) ((float*)out)[orow * N + col] = v;
          else ((__bf16*)out)[orow * N + col] = (__bf16)v;
        }
      }
    }
  }
}

// ---------------- final combine: out[t] = g0*Y[p0] + g1*Y[p1] ----------------
__global__ void combine_kernel(const float* __restrict__ Y, const int* __restrict__ route_pos,
                               const float2* __restrict__ g01, float* __restrict__ out) {
  int gid = blockIdx.x * blockDim.x + threadIdx.x;
  int t = gid >> 6, c = (gid & 63) << 2;
  if (t >= NTOK) return;
  int p0 = route_pos[2 * t], p1 = route_pos[2 * t + 1];
  float2 g = g01[t];
  float4 y0 = *(const float4*)&Y[(size_t)p0 * DOUT + c];
  float4 y1 = *(const float4*)&Y[(size_t)p1 * DOUT + c];
  float4 o;
  o.x = g.x * y0.x + g.y * y1.x;
  o.y = g.x * y0.y + g.y * y1.y;
  o.z = g.x * y0.z + g.y * y1.z;
  o.w = g.x * y0.w + g.y * y1.w;
  *(float4*)&out[(size_t)t * DOUT + c] = o;
}

// ---------------- launcher ----------------
extern "C" void kernel_launch(void* const* d_in, const int* in_sizes, int n_in,
                              void* d_out, int out_size, void* d_ws, size_t ws_size,
                              hipStream_t stream) {
  const float* x          = (const float*)d_in[0];
  const float* gate_w     = (const float*)d_in[1];
  const float* gate_b     = (const float*)d_in[2];
  const float* gate_out_w = (const float*)d_in[3];
  const float* gate_out_b = (const float*)d_in[4];
  const float* w1         = (const float*)d_in[5];
  const float* b1         = (const float*)d_in[6];
  const float* w2         = (const float*)d_in[7];
  const float* b2         = (const float*)d_in[8];
  const float* w3         = (const float*)d_in[9];
  const float* b3         = (const float*)d_in[10];
  float* out = (float*)d_out;

  char* ws = (char*)d_ws;
  size_t o = 0;
  auto alloc = [&](size_t bytes) -> void* {
    o = (o + 255) & ~(size_t)255;
    void* p = ws + o;
    o += bytes;
    return p;
  };

  __bf16* xb   = (__bf16*)alloc((size_t)NTOK * DIN * 2);
  __bf16* w1t  = (__bf16*)alloc((size_t)NEXP * HID * DIN * 2);
  __bf16* w2t  = (__bf16*)alloc((size_t)NEXP * HID * HID * 2);
  __bf16* w3t  = (__bf16*)alloc((size_t)NEXP * DOUT * HID * 2);
  __bf16* gwt  = (__bf16*)alloc((size_t)HID * GK * 2);
  __bf16* H1   = (__bf16*)alloc((size_t)(NKA + 128) * HID * 2);
  // xs (gate split input, dead after gate GEMM) aliases H2 (written much later)
  size_t r3 = (size_t)NTOK * GK * 2;
  size_t r4 = (size_t)(NKA + 128) * HID * 2;
  void* region2 = alloc(r3 > r4 ? r3 : r4);
  __bf16* xs = (__bf16*)region2;
  __bf16* H2 = (__bf16*)region2;
  float* logits    = (float*)alloc((size_t)NTOK * 16 * 4);
  int2*  e01       = (int2*)alloc((size_t)NTOK * 8);
  float2* g01      = (float2*)alloc((size_t)NTOK * 8);
  int*   offsets   = (int*)alloc((NEXP + 1) * 4);
  int*   blockhist = (int*)alloc((size_t)NBLK * NEXP * 4);
  int*   base      = (int*)alloc((size_t)NBLK * NEXP * 4);
  int*   lrank     = (int*)alloc((size_t)NTOK * 2 * 4);
  int*   tok_sorted= (int*)alloc((size_t)(NKA + 128) * 4);
  int*   route_pos = (int*)alloc((size_t)NTOK * 2 * 4);
  int*   tile_e    = (int*)alloc(MAXTILE * 4);
  int*   tile_mt   = (int*)alloc(MAXTILE * 4);
  int*   ntiles    = (int*)alloc(4);
  int*   gtile_e   = (int*)alloc(128 * 4);
  int*   gtile_mt  = (int*)alloc(128 * 4);
  int*   gntiles   = (int*)alloc(4);
  int*   gseg      = (int*)alloc(2 * 4);
  float*  Y        = (float*)alloc((size_t)(NKA + 128) * DOUT * 4);
  (void)ws_size; (void)n_in; (void)in_sizes; (void)out_size;

  // 1. fused prep (cvt_x + gate weight split + 3 weight transposes + zero(logits))
  prep_kernel<<<10496, 256, 0, stream>>>(x, xb, xs, gate_w, gwt,
                                         w1, w1t, w2, w2t, w3, w3t,
                                         gtile_e, gtile_mt, gntiles, gseg, logits);

  // 2. gate GEMM (bf16x2-split K=768) with fused logits epilogue -> logits
  moe_gemm_kernel<3, true><<<dim3(NTOK / 64, HID / 128), 256, 0, stream>>>(
      xs, gwt, gate_b, logits, gseg, nullptr, gtile_e, gtile_mt, gntiles,
      gate_out_w, GK, HID);

  // 3-5. top-2 routing + scan + fill
  top2_kernel<<<NBLK, 256, 0, stream>>>(logits, gate_out_b, e01, g01, lrank, blockhist);
  scan2_kernel<<<1, 64, 0, stream>>>(blockhist, offsets, base, tile_e, tile_mt, ntiles);
  fill2_kernel<<<NBLK, 256, 0, stream>>>(e01, lrank, base, tok_sorted, route_pos);

  // 6-8. expert GEMMs
  moe_gemm_kernel<0, true><<<dim3(MAXTILE, HID / 128), 256, 0, stream>>>(
      xb, w1t, b1, H1, offsets, tok_sorted, tile_e, tile_mt, ntiles,
      nullptr, DIN, HID);
  moe_gemm_kernel<0, true><<<dim3(MAXTILE, HID / 128), 256, 0, stream>>>(
      H1, w2t, b2, H2, offsets, nullptr, tile_e, tile_mt, ntiles,
      nullptr, HID, HID);
  moe_gemm_kernel<1, false><<<dim3(MAXTILE, DOUT / 128), 256, 0, stream>>>(
      H2, w3t, b3, Y, offsets, nullptr, tile_e, tile_mt, ntiles,
      nullptr, HID, DOUT);

  // 9. combine
  combine_kernel<<<(NTOK * 64) / 256, 256, 0, stream>>>(Y, route_pos, g01, out);
}